// Round 1
// 2005.184 us; speedup vs baseline: 1.4404x; 1.4404x over previous
//
#include <hip/hip_runtime.h>
#include <stdint.h>

#define NEGVAL -1000000000.0f

typedef __attribute__((ext_vector_type(4))) float floatx4;
typedef __attribute__((ext_vector_type(8))) __bf16 bf16x8;
typedef unsigned short u16;

__device__ __forceinline__ u16 f2bf(float f) {
  uint32_t u = __float_as_uint(f);
  u += 0x7fffu + ((u >> 16) & 1u);   // round-to-nearest-even
  return (u16)(u >> 16);
}

// ---------------- elementwise fp32 -> bf16 cast of x ----------------
__global__ void convert_x_kernel(const float* __restrict__ x, u16* __restrict__ xb, int n4) {
  int i = blockIdx.x * blockDim.x + threadIdx.x;
  if (i < n4) {
    float4 f = reinterpret_cast<const float4*>(x)[i];
    ushort4 o;
    o.x = f2bf(f.x); o.y = f2bf(f.y); o.z = f2bf(f.z); o.w = f2bf(f.w);
    reinterpret_cast<ushort4*>(xb)[i] = o;
  }
}

// ---------------- W (k,n) fp32 -> WT (n,k) bf16 ----------------
__global__ void transpose_w_kernel(const float* __restrict__ W0, const float* __restrict__ W1,
                                   const float* __restrict__ W2, const float* __restrict__ W3,
                                   u16* __restrict__ T0, u16* __restrict__ T1,
                                   u16* __restrict__ T2, u16* __restrict__ T3) {
  __shared__ float tile[32][33];
  int z = blockIdx.z;
  const float* W = (z == 0) ? W0 : (z == 1) ? W1 : (z == 2) ? W2 : W3;
  u16* T = (z == 0) ? T0 : (z == 1) ? T1 : (z == 2) ? T2 : T3;
  int r0 = blockIdx.y * 32, c0 = blockIdx.x * 32;
  int t = threadIdx.x;
#pragma unroll
  for (int j = 0; j < 4; j++) {
    int idx = t + j * 256; int r = idx >> 5, c = idx & 31;
    tile[r][c] = W[(size_t)(r0 + r) * 1024 + c0 + c];
  }
  __syncthreads();
#pragma unroll
  for (int j = 0; j < 4; j++) {
    int idx = t + j * 256; int r = idx >> 5, c = idx & 31;
    T[(size_t)(c0 + r) * 1024 + r0 + c] = f2bf(tile[c][r]);
  }
}

// ---------------- bf16 MFMA GEMM: C[m][n] = sum_k A[m][k]*Bt[n][k] (+bias, mode-specific epilogue)
__launch_bounds__(256)
__global__ void gemm_bt_kernel(const u16* __restrict__ A,
                               const u16* __restrict__ BtQ, const u16* __restrict__ BtK, const u16* __restrict__ BtV,
                               const float* __restrict__ biasQ, const float* __restrict__ biasK, const float* __restrict__ biasV,
                               const float* __restrict__ xres,
                               u16* __restrict__ Qb, u16* __restrict__ Kb, u16* __restrict__ Vt,
                               float* __restrict__ outpre,
                               int out_mode) {
  const int mode = (out_mode == 3) ? 3 : (int)blockIdx.z;
  const u16* Bt = (mode == 1) ? BtK : (mode == 2) ? BtV : BtQ;
  const float* bias = (mode == 1) ? biasK : (mode == 2) ? biasV : biasQ;

  __shared__ u16 As[64][40];
  __shared__ u16 Bs[64][40];

  int tid = threadIdx.x;
  int w = tid >> 6, lane = tid & 63, quad = lane >> 4, l16 = lane & 15;
  int m0 = blockIdx.y * 64, n0 = blockIdx.x * 64;
  const int Kdim = 1024;

  floatx4 acc[4] = {};
  int srow = tid >> 2, scol = (tid & 3) * 8;

  for (int k0 = 0; k0 < Kdim; k0 += 32) {
    __syncthreads();
    uint4 av = *reinterpret_cast<const uint4*>(&A[(size_t)(m0 + srow) * Kdim + k0 + scol]);
    *reinterpret_cast<uint4*>(&As[srow][scol]) = av;
    uint4 bv = *reinterpret_cast<const uint4*>(&Bt[(size_t)(n0 + srow) * Kdim + k0 + scol]);
    *reinterpret_cast<uint4*>(&Bs[srow][scol]) = bv;
    __syncthreads();
    bf16x8 af = *reinterpret_cast<const bf16x8*>(&As[w * 16 + l16][quad * 8]);
#pragma unroll
    for (int nt = 0; nt < 4; nt++) {
      bf16x8 bfr = *reinterpret_cast<const bf16x8*>(&Bs[nt * 16 + l16][quad * 8]);
      acc[nt] = __builtin_amdgcn_mfma_f32_16x16x32_bf16(af, bfr, acc[nt], 0, 0, 0);
    }
  }

  int mrow_base = m0 + w * 16 + quad * 4;
  if (mode == 3) {
#pragma unroll
    for (int nt = 0; nt < 4; nt++) {
      int n = n0 + nt * 16 + l16;
      float bn = bias[n];
#pragma unroll
      for (int r = 0; r < 4; r++) {
        size_t idx = (size_t)(mrow_base + r) * 1024 + n;
        outpre[idx] = acc[nt][r] + bn + xres[idx];
      }
    }
  } else {
    int b = m0 >> 11;
    int h = n0 >> 6;
#pragma unroll
    for (int nt = 0; nt < 4; nt++) {
      int dk = nt * 16 + l16;
      float bn = bias[n0 + dk];
      if (mode == 2) {
        ushort4 pk;
        pk.x = f2bf(acc[nt][0] + bn);
        pk.y = f2bf(acc[nt][1] + bn);
        pk.z = f2bf(acc[nt][2] + bn);
        pk.w = f2bf(acc[nt][3] + bn);
        int s = mrow_base & 2047;
        *reinterpret_cast<ushort4*>(&Vt[((size_t)(b * 16 + h) * 64 + dk) * 2048 + s]) = pk;
      } else {
        float scale = (mode == 0) ? 0.125f : 1.0f;
        u16* dst = (mode == 0) ? Qb : Kb;
#pragma unroll
        for (int r = 0; r < 4; r++) {
          int s = (mrow_base + r) & 2047;
          dst[((size_t)(b * 16 + h) * 2048 + s) * 64 + dk] = f2bf((acc[nt][r] + bn) * scale);
        }
      }
    }
  }
}

// ---------------- fused attention v2 ----------------
// 512 threads (8 waves), 16 q rows per block. Two-pass softmax (recompute QK^T),
// bf16 e-values in 64KB XOR-swizzled LDS -> 2 blocks/CU (4 waves/SIMD).
// LDS swizzle: byte = (row<<12) + ((col*2) ^ ((row&7)<<4))  -- 16B-chunk XOR, G4/T2 pattern.
__launch_bounds__(512, 4)
__global__ void attn_kernel(const u16* __restrict__ Qb, const u16* __restrict__ Kb,
                            const u16* __restrict__ Vt, const int* __restrict__ mask,
                            float* __restrict__ att, u16* __restrict__ ctxb) {
  extern __shared__ char smem[];          // 65536 B: u16 e[16 rows][2048], swizzled
  __shared__ float redmax[8][16];
  __shared__ float redsum[8][16];
  __shared__ float qinv_s[16];

  int tid = threadIdx.x;
  int w = tid >> 6, lane = tid & 63, quad = lane >> 4, l16 = lane & 15;
  int bh = blockIdx.y, b = bh >> 4, h = bh & 15;
  int q0 = blockIdx.x * 16;

  // Q fragments: rows q0+l16, dims quad*8..+7 and +32
  size_t qbase = ((size_t)bh * 2048 + q0 + l16) * 64 + quad * 8;
  bf16x8 a0 = *reinterpret_cast<const bf16x8*>(&Qb[qbase]);
  bf16x8 a1 = *reinterpret_cast<const bf16x8*>(&Qb[qbase + 32]);

  // ---- pass 1: QK^T, per-row max online (no LDS). wave w covers kp = i*128 + w*16
  float m[4] = {-3.4e38f, -3.4e38f, -3.4e38f, -3.4e38f};
  unsigned mvbits = 0;
  for (int i = 0; i < 16; i++) {
    int kp = i * 128 + w * 16;
    size_t kbase = ((size_t)bh * 2048 + kp + l16) * 64 + quad * 8;
    bf16x8 b0 = *reinterpret_cast<const bf16x8*>(&Kb[kbase]);
    bf16x8 b1 = *reinterpret_cast<const bf16x8*>(&Kb[kbase + 32]);
    floatx4 s4 = {};
    s4 = __builtin_amdgcn_mfma_f32_16x16x32_bf16(a0, b0, s4, 0, 0, 0);
    s4 = __builtin_amdgcn_mfma_f32_16x16x32_bf16(a1, b1, s4, 0, 0, 0);
    int kidx = kp + l16;
    int mv = mask[(b << 11) + kidx];
    mvbits |= (mv ? 1u : 0u) << i;
#pragma unroll
    for (int r = 0; r < 4; r++) {
      float sm = mv ? s4[r] : NEGVAL;
      m[r] = fmaxf(m[r], sm);
    }
  }
  // reduce max across the 16 lanes of each quad (rows quad*4+r live on l16 group)
#pragma unroll
  for (int d = 1; d < 16; d <<= 1) {
#pragma unroll
    for (int r = 0; r < 4; r++) m[r] = fmaxf(m[r], __shfl_xor(m[r], d, 16));
  }
  if (l16 == 0) {
#pragma unroll
    for (int r = 0; r < 4; r++) redmax[w][quad * 4 + r] = m[r];
  }
  __syncthreads();
  float gm[4];
#pragma unroll
  for (int r = 0; r < 4; r++) {
    float g = redmax[0][quad * 4 + r];
#pragma unroll
    for (int w2 = 1; w2 < 8; w2++) g = fmaxf(g, redmax[w2][quad * 4 + r]);
    gm[r] = g;
  }

  // ---- pass 2: recompute QK^T, e = exp(s-gm), row sums, bf16 e -> swizzled LDS
  float sum[4] = {0.f, 0.f, 0.f, 0.f};
  for (int i = 0; i < 16; i++) {
    int kp = i * 128 + w * 16;
    size_t kbase = ((size_t)bh * 2048 + kp + l16) * 64 + quad * 8;
    bf16x8 b0 = *reinterpret_cast<const bf16x8*>(&Kb[kbase]);
    bf16x8 b1 = *reinterpret_cast<const bf16x8*>(&Kb[kbase + 32]);
    floatx4 s4 = {};
    s4 = __builtin_amdgcn_mfma_f32_16x16x32_bf16(a0, b0, s4, 0, 0, 0);
    s4 = __builtin_amdgcn_mfma_f32_16x16x32_bf16(a1, b1, s4, 0, 0, 0);
    int kidx = kp + l16;
    int mv = (mvbits >> i) & 1;
#pragma unroll
    for (int r = 0; r < 4; r++) {
      int row = quad * 4 + r;
      float e = mv ? __expf(s4[r] - gm[r]) : 0.0f;
      sum[r] += e;
      *reinterpret_cast<u16*>(smem + (((row << 12) + (kidx << 1)) ^ ((row & 7) << 4))) = f2bf(e);
    }
  }
#pragma unroll
  for (int d = 1; d < 16; d <<= 1) {
#pragma unroll
    for (int r = 0; r < 4; r++) sum[r] += __shfl_xor(sum[r], d, 16);
  }
  if (l16 == 0) {
#pragma unroll
    for (int r = 0; r < 4; r++) redsum[w][quad * 4 + r] = sum[r];
  }
  __syncthreads();
  if (tid < 16) {
    float t = 0.f;
#pragma unroll
    for (int w2 = 0; w2 < 8; w2++) t += redsum[w2][tid];
    qinv_s[tid] = 1.0f / t;
  }
  __syncthreads();

  // ---- att write: LDS bf16 -> fp32 * qinv, fully coalesced (32B/lane stores)
  size_t attbase = ((size_t)bh * 2048 + q0) * 2048;
#pragma unroll
  for (int it = 0; it < 8; it++) {
    int row = it * 2 + (tid >> 8);
    int colb = (tid & 255) << 4;   // byte offset in row, 16B chunk per thread
    uint4 v = *reinterpret_cast<const uint4*>(smem + ((row << 12) + (colb ^ ((row & 7) << 4))));
    float inv = qinv_s[row];
    float4 o0, o1;
    o0.x = __uint_as_float((v.x & 0xffffu) << 16) * inv;
    o0.y = __uint_as_float(v.x & 0xffff0000u) * inv;
    o0.z = __uint_as_float((v.y & 0xffffu) << 16) * inv;
    o0.w = __uint_as_float(v.y & 0xffff0000u) * inv;
    o1.x = __uint_as_float((v.z & 0xffffu) << 16) * inv;
    o1.y = __uint_as_float(v.z & 0xffff0000u) * inv;
    o1.z = __uint_as_float((v.w & 0xffffu) << 16) * inv;
    o1.w = __uint_as_float(v.w & 0xffff0000u) * inv;
    float* ap = att + attbase + (size_t)row * 2048 + ((tid & 255) << 3);
    reinterpret_cast<float4*>(ap)[0] = o0;
    reinterpret_cast<float4*>(ap)[1] = o1;
  }

  // ---- PV: 8 waves, dk strip (w&3)*16, k half (w>>2)*1024; combine halves via LDS scratch
  int dk0 = (w & 3) * 16;
  int kh = (w >> 2) * 1024;
  floatx4 pacc = {};
  for (int j = 0; j < 32; j++) {
    int kp = kh + j * 32;
    bf16x8 pa = *reinterpret_cast<const bf16x8*>(
        smem + ((l16 << 12) + ((((kp + quad * 8) << 1)) ^ ((l16 & 7) << 4))));
    bf16x8 pb = *reinterpret_cast<const bf16x8*>(
        &Vt[((size_t)bh * 64 + dk0 + l16) * 2048 + kp + quad * 8]);
    pacc = __builtin_amdgcn_mfma_f32_16x16x32_bf16(pa, pb, pacc, 0, 0, 0);
  }
  __syncthreads();               // all sc reads done; safe to reuse smem as scratch
  float* scf = reinterpret_cast<float*>(smem);
  if (w >= 4) {
#pragma unroll
    for (int r = 0; r < 4; r++) scf[(((w - 4) * 64) + lane) * 4 + r] = pacc[r];
  }
  __syncthreads();
  if (w < 4) {
#pragma unroll
    for (int r = 0; r < 4; r++) {
      float val = pacc[r] + scf[((w * 64) + lane) * 4 + r];
      int row = quad * 4 + r;
      val *= qinv_s[row];
      int sidx = q0 + row;
      ctxb[((size_t)(b * 2048 + sidx)) * 1024 + h * 64 + dk0 + l16] = f2bf(val);
    }
  }
}

// ---------------- LayerNorm over rows of 1024 ----------------
__launch_bounds__(256)
__global__ void ln_kernel(const float* __restrict__ outpre, const float* __restrict__ gamma,
                          const float* __restrict__ beta, float* __restrict__ outF) {
  __shared__ float r1[256], r2[256];
  int row = blockIdx.x, t = threadIdx.x;
  float4 v = reinterpret_cast<const float4*>(outpre + (size_t)row * 1024)[t];
  r1[t] = v.x + v.y + v.z + v.w;
  r2[t] = v.x * v.x + v.y * v.y + v.z * v.z + v.w * v.w;
  __syncthreads();
  for (int st = 128; st > 0; st >>= 1) {
    if (t < st) { r1[t] += r1[t + st]; r2[t] += r2[t + st]; }
    __syncthreads();
  }
  float mu = r1[0] * (1.0f / 1024.0f);
  float var = r2[0] * (1.0f / 1024.0f) - mu * mu;
  float rs = rsqrtf(var + 1e-5f);
  float4 g = reinterpret_cast<const float4*>(gamma)[t];
  float4 bt = reinterpret_cast<const float4*>(beta)[t];
  float4 o;
  o.x = (v.x - mu) * rs * g.x + bt.x;
  o.y = (v.y - mu) * rs * g.y + bt.y;
  o.z = (v.z - mu) * rs * g.z + bt.z;
  o.w = (v.w - mu) * rs * g.w + bt.w;
  reinterpret_cast<float4*>(outF + (size_t)row * 1024)[t] = o;
}

extern "C" void kernel_launch(void* const* d_in, const int* in_sizes, int n_in,
                              void* d_out, int out_size, void* d_ws, size_t ws_size,
                              hipStream_t stream) {
  (void)in_sizes; (void)n_in; (void)out_size; (void)ws_size;
  const float* x     = (const float*)d_in[0];
  const int*   mask  = (const int*)d_in[1];
  const float* Wq    = (const float*)d_in[2];
  const float* bq    = (const float*)d_in[3];
  const float* Wk    = (const float*)d_in[4];
  const float* bk    = (const float*)d_in[5];
  const float* Wv    = (const float*)d_in[6];
  const float* bv    = (const float*)d_in[7];
  const float* Wo    = (const float*)d_in[8];
  const float* bo    = (const float*)d_in[9];
  const float* gamma = (const float*)d_in[10];
  const float* beta  = (const float*)d_in[11];

  float* out = (float*)d_out;
  float* att = out + (size_t)8192 * 1024;

  char* ws = (char*)d_ws;
  u16*   xb     = (u16*)(ws);
  u16*   WqT    = (u16*)(ws + 16777216);
  u16*   WkT    = (u16*)(ws + 18874368);
  u16*   WvT    = (u16*)(ws + 20971520);
  u16*   WoT    = (u16*)(ws + 23068672);
  u16*   Qb     = (u16*)(ws + 25165824);
  u16*   Kb     = (u16*)(ws + 41943040);
  u16*   Vt     = (u16*)(ws + 58720256);
  u16*   ctxb   = (u16*)(ws + 75497472);
  float* outpre = (float*)(ws + 92274688);

  convert_x_kernel<<<8192, 256, 0, stream>>>(x, xb, 2097152);
  transpose_w_kernel<<<dim3(32, 32, 4), 256, 0, stream>>>(Wq, Wk, Wv, Wo, WqT, WkT, WvT, WoT);
  gemm_bt_kernel<<<dim3(16, 128, 3), 256, 0, stream>>>(xb, WqT, WkT, WvT, bq, bk, bv, nullptr,
                                                       Qb, Kb, Vt, nullptr, 0);
  size_t scbytes = 65536;   // bf16 e-tile, 16 x 2048, XOR-swizzled
  hipFuncSetAttribute(reinterpret_cast<const void*>(attn_kernel),
                      hipFuncAttributeMaxDynamicSharedMemorySize, (int)scbytes);
  attn_kernel<<<dim3(128, 64), 512, scbytes, stream>>>(Qb, Kb, Vt, mask, att, ctxb);
  gemm_bt_kernel<<<dim3(16, 128, 1), 256, 0, stream>>>(ctxb, WoT, nullptr, nullptr, bo, nullptr, nullptr, x,
                                                       nullptr, nullptr, nullptr, outpre, 3);
  ln_kernel<<<8192, 256, 0, stream>>>(outpre, gamma, beta, out);
}